// Round 3
// baseline (254.112 us; speedup 1.0000x reference)
//
#include <hip/hip_runtime.h>
#include <hip/hip_fp16.h>
#include <hip/hip_cooperative_groups.h>
#include <math.h>

namespace cg = cooperative_groups;

#define IN_DIM 128
#define OUT_DIM 64
#define NEG_SLOPE 0.2f

// Bucket = 32 consecutive src ids. CAP = 1024 edges/bucket (mean 512 for
// E=800K,N=50K). N < 65536 so dst fits 16 bits in the packed word.
#define BUCKET_SRCS 32
#define CAP 1024
#define MAXBK 2048

typedef _Float16 half8 __attribute__((ext_vector_type(8)));
typedef float floatx4 __attribute__((ext_vector_type(4)));

#define GR 64
#define PA_CHUNK 8192

// ===========================================================================
// R15: cooperative single-kernel path (memset + partition + gemm + node fused,
// two grid.sync()s), with an occupancy-queried grid and an error-checked
// fallback to the proven 3-dispatch path. R14's fail was almost certainly a
// rejected launch (grid == exact occupancy max, return code unchecked) ->
// zero output (absmax == max|ref| == 3.2969).
// Work queues live at gcursor[MAXBK-2] / gcursor[MAXBK-1] (buckets stop at
// NBK-1 = 1562), keeping pairbuf 16B-aligned at gcursor+MAXBK.
// ===========================================================================
__global__ __launch_bounds__(256, 2) void gat_all(
    const float* __restrict__ in, const float* __restrict__ W,
    const float* __restrict__ a, __half* __restrict__ hb,
    float* __restrict__ hs, float* __restrict__ hd,
    const int* __restrict__ src, const int* __restrict__ dst,
    int* __restrict__ gcursor, int* __restrict__ pairbuf,
    float* __restrict__ out,
    int E, int NBK, int PB, int NITEM, int N)
{
    __shared__ union {
        struct { _Float16 Al[GR][IN_DIM]; _Float16 Wt[OUT_DIM][IN_DIM + 8]; } g;
        struct { int lcount[MAXBK]; int lbase[MAXBK]; int lrun[MAXBK]; } p;
        struct { int2 spair[CAP]; float hsl[BUCKET_SRCS];
                 int cnt[BUCKET_SRCS]; int excl[BUCKET_SRCS];
                 int lcur[BUCKET_SRCS]; int perm[BUCKET_SRCS]; } n;
    } sm;
    __shared__ int s_item;          // work-queue broadcast (outside union!)

    const int t = threadIdx.x;
    cg::grid_group grid = cg::this_grid();

    // ---- phase 0: zero gcursor (incl. the two work-queue slots) ----------
    for (int i = blockIdx.x * 256 + t; i < MAXBK; i += gridDim.x * 256)
        gcursor[i] = 0;

    __threadfence();
    grid.sync();

    int* wqA = &gcursor[MAXBK - 2];
    int* wqB = &gcursor[MAXBK - 1];

    // ---- phase A: partition chunks (item<PB) + gemm tiles ----------------
    for (;;) {
        __syncthreads();              // protect prior body's LDS + s_item
        if (t == 0) s_item = atomicAdd(wqA, 1);
        __syncthreads();
        const int item = s_item;
        if (item >= NITEM) break;     // block-uniform

        if (item < PB) {
            // ----------------------- partition -----------------------------
            for (int i = t; i < NBK; i += 256) sm.p.lcount[i] = 0;
            __syncthreads();

            const int base = item * PA_CHUNK;
            int w[32];
            int nev = 0;
            #pragma unroll
            for (int j = 0; j < 8; ++j) {
                int i = base + j * 1024 + t * 4;
                if (i + 3 < E) {
                    int4 s4 = *(const int4*)&src[i];
                    int4 d4 = *(const int4*)&dst[i];
                    int b0 = s4.x >> 5, b1 = s4.y >> 5, b2 = s4.z >> 5, b3 = s4.w >> 5;
                    w[4 * j + 0] = (b0 << 21) | ((s4.x & 31) << 16) | d4.x;
                    w[4 * j + 1] = (b1 << 21) | ((s4.y & 31) << 16) | d4.y;
                    w[4 * j + 2] = (b2 << 21) | ((s4.z & 31) << 16) | d4.z;
                    w[4 * j + 3] = (b3 << 21) | ((s4.w & 31) << 16) | d4.w;
                    atomicAdd(&sm.p.lcount[b0], 1);
                    atomicAdd(&sm.p.lcount[b1], 1);
                    atomicAdd(&sm.p.lcount[b2], 1);
                    atomicAdd(&sm.p.lcount[b3], 1);
                    nev = 4 * j + 4;
                } else {
                    #pragma unroll
                    for (int u = 0; u < 4; ++u) {
                        if (i + u < E) {
                            int s = src[i + u];
                            int d = dst[i + u];
                            int bb = s >> 5;
                            w[4 * j + u] = (bb << 21) | ((s & 31) << 16) | d;
                            atomicAdd(&sm.p.lcount[bb], 1);
                            nev = 4 * j + u + 1;
                        }
                    }
                }
            }
            __syncthreads();
            for (int i = t; i < NBK; i += 256) {
                int c = sm.p.lcount[i];
                int gb = 0;
                if (c > 0) gb = atomicAdd(&gcursor[i], c);
                sm.p.lbase[i] = i * CAP + gb;
                sm.p.lrun[i] = 0;
            }
            __syncthreads();
            #pragma unroll
            for (int k = 0; k < 32; ++k) {
                if (k < nev) {
                    int bb = ((unsigned)w[k]) >> 21;
                    int r = atomicAdd(&sm.p.lrun[bb], 1);
                    int pos = sm.p.lbase[bb] + r;
                    if (pos - bb * CAP < CAP)     // capacity guard
                        pairbuf[pos] = w[k];
                }
            }
        } else {
            // ------------------------- gemm --------------------------------
            const int r0 = (item - PB) * GR;

            #pragma unroll
            for (int i = 0; i < 8; ++i) {
                int q = i * 256 + t;
                int row = q >> 5;
                int kq  = (q & 31) * 4;
                int grow = r0 + row; if (grow >= N) grow = N - 1;
                float4 v = *(const float4*)&in[(size_t)grow * IN_DIM + kq];
                union { __half2 h2[2]; uint2 u; } cv;
                cv.h2[0] = __floats2half2_rn(v.x, v.y);
                cv.h2[1] = __floats2half2_rn(v.z, v.w);
                *(uint2*)&sm.g.Al[row][kq] = cv.u;
            }
            #pragma unroll
            for (int i = 0; i < 8; ++i) {
                int q = i * 256 + t;
                int k  = q >> 4;
                int n4 = (q & 15) * 4;
                float4 v = *(const float4*)&W[(size_t)k * OUT_DIM + n4];
                sm.g.Wt[n4 + 0][k] = (_Float16)v.x;
                sm.g.Wt[n4 + 1][k] = (_Float16)v.y;
                sm.g.Wt[n4 + 2][k] = (_Float16)v.z;
                sm.g.Wt[n4 + 3][k] = (_Float16)v.w;
            }
            __syncthreads();

            const int lane = t & 63;
            const int wave = t >> 6;
            const int m16  = lane & 15;
            const int quad = lane >> 4;

            floatx4 acc[4];
            #pragma unroll
            for (int nt = 0; nt < 4; ++nt) acc[nt] = (floatx4){0.f, 0.f, 0.f, 0.f};

            #pragma unroll
            for (int kc = 0; kc < 4; ++kc) {
                half8 af = *(const half8*)&sm.g.Al[wave * 16 + m16][kc * 32 + quad * 8];
                #pragma unroll
                for (int nt = 0; nt < 4; ++nt) {
                    half8 bf = *(const half8*)&sm.g.Wt[nt * 16 + m16][kc * 32 + quad * 8];
                    acc[nt] = __builtin_amdgcn_mfma_f32_16x16x32_f16(af, bf, acc[nt], 0, 0, 0);
                }
            }
            __syncthreads();   // Al dead from here; Crep aliases it

            _Float16 (*Crep)[OUT_DIM + 8] = (_Float16(*)[OUT_DIM + 8])&sm.g.Al[0][0];

            float asl[4], adl[4];
            #pragma unroll
            for (int nt = 0; nt < 4; ++nt) {
                asl[nt] = a[nt * 16 + m16];
                adl[nt] = a[OUT_DIM + nt * 16 + m16];
            }
            #pragma unroll
            for (int r = 0; r < 4; ++r) {
                float ps = 0.f, pd = 0.f;
                #pragma unroll
                for (int nt = 0; nt < 4; ++nt) {
                    ps = fmaf(acc[nt][r], asl[nt], ps);
                    pd = fmaf(acc[nt][r], adl[nt], pd);
                }
                #pragma unroll
                for (int off = 1; off < 16; off <<= 1) {
                    ps += __shfl_xor(ps, off, 64);
                    pd += __shfl_xor(pd, off, 64);
                }
                if (m16 == 0) {
                    int row = r0 + wave * 16 + quad * 4 + r;
                    if (row < N) { hs[row] = ps; hd[row] = pd; }
                }
            }

            #pragma unroll
            for (int nt = 0; nt < 4; ++nt)
                #pragma unroll
                for (int r = 0; r < 4; ++r)
                    Crep[wave * 16 + quad * 4 + r][nt * 16 + m16] = (_Float16)acc[nt][r];
            __syncthreads();
            #pragma unroll
            for (int i = 0; i < 2; ++i) {
                int idx = i * 256 + t;
                int row = idx >> 3;
                int seg = idx & 7;
                int gr2 = r0 + row;
                if (gr2 < N) {
                    uint4 v = *(const uint4*)&Crep[row][seg * 8];
                    *(uint4*)&hb[(size_t)gr2 * OUT_DIM + seg * 8] = v;
                }
            }
        }
    }

    // ---- phase boundary: producer release, barrier, consumer acquire -----
    __threadfence();
    grid.sync();
    __threadfence();

    // ---- phase B: node aggregation, dynamic bucket queue -----------------
    for (;;) {
        __syncthreads();              // protect prior bucket's LDS + s_item
        if (t == 0) s_item = atomicAdd(wqB, 1);
        __syncthreads();
        const int b = s_item;
        if (b >= NBK) break;          // block-uniform

        const int M = min(gcursor[b], CAP);

        if (t < BUCKET_SRCS) {
            int node = b * BUCKET_SRCS + t;
            sm.n.hsl[t] = (node < N) ? hs[node] : 0.f;
            sm.n.cnt[t] = 0;
        }
        __syncthreads();

        const int i0 = t * 4;
        int4 p4 = *(const int4*)&pairbuf[b * CAP + i0];
        int   pkv[4] = {p4.x, p4.y, p4.z, p4.w};
        int   dofs[4], slv[4];
        float exv[4];
        int nl = 0;
        #pragma unroll
        for (int u = 0; u < 4; ++u) {
            if (i0 + u < M) {
                int pk = pkv[u];
                int sl = (pk >> 16) & 31;
                int d  = pk & 0xffff;
                float e = sm.n.hsl[sl] + hd[d];
                e = (e >= 0.f) ? e : NEG_SLOPE * e;
                exv[u]  = __expf(e);
                slv[u]  = sl;
                dofs[u] = d << 7;                 // byte offset: d*OUT_DIM*2
                atomicAdd(&sm.n.cnt[sl], 1);
                nl = u + 1;
            }
        }
        __syncthreads();
        if (t < BUCKET_SRCS) {
            int raw = sm.n.cnt[t];
            int v = raw;
            #pragma unroll
            for (int off = 1; off < BUCKET_SRCS; off <<= 1) {
                int u = __shfl_up(v, off, 64);
                if (t >= off) v += u;
            }
            sm.n.excl[t] = v - raw;
            sm.n.lcur[t] = v - raw;

            // bitonic sort (ascending) of key = deg*32 + idx, lanes 0..31
            int key = raw * 32 + t;
            #pragma unroll
            for (int k = 2; k <= 32; k <<= 1) {
                #pragma unroll
                for (int j = k >> 1; j > 0; j >>= 1) {
                    int other = __shfl_xor(key, j, 64);
                    bool up = (t & k) == 0;
                    bool lower = (t & j) == 0;
                    int mn = min(key, other), mx = max(key, other);
                    key = (up == lower) ? mn : mx;
                }
            }
            sm.n.perm[t] = key & 31;   // rank t -> original node-local index
        }
        __syncthreads();
        #pragma unroll
        for (int u = 0; u < 4; ++u) {
            if (u < nl) {
                int r = atomicAdd(&sm.n.lcur[slv[u]], 1);
                sm.n.spair[r] = make_int2(__float_as_int(exv[u]), dofs[u]);
            }
        }
        __syncthreads();

        // phase 2: slot = node (degree-balanced via perm)
        const int lane = t & 63;
        const int wave = t >> 6;
        const int slot = lane >> 3;
        const int c8   = lane & 7;
        const int loc  = sm.n.perm[wave * 8 + slot];
        const int node = b * BUCKET_SRCS + loc;
        const bool valid = node < N;

        const int deg = sm.n.cnt[loc];
        const int beg = sm.n.excl[loc];

        int dmax = deg;
        #pragma unroll
        for (int off = 8; off < 64; off <<= 1)
            dmax = max(dmax, __shfl_xor(dmax, off, 64));

        const char* hbp = (const char*)hb + c8 * 16;   // lane-constant base

        float acc[8];
        float ssum = 0.f;
        #pragma unroll
        for (int q = 0; q < 8; ++q) acc[q] = 0.f;

        for (int j = 0; j < dmax; j += 4) {
            int2 pr[4];
            float ex[4];
            #pragma unroll
            for (int u = 0; u < 4; ++u) {
                bool act = j + u < deg;
                pr[u] = sm.n.spair[beg + (act ? j + u : 0)];
                ex[u] = act ? __int_as_float(pr[u].x) : 0.f;
                ssum += ex[u];
            }
            union { uint4 u4; __half2 h2[4]; } hv[4];
            #pragma unroll
            for (int u = 0; u < 4; ++u)
                hv[u].u4 = *(const uint4*)(hbp + pr[u].y);   // add-only addr
            #pragma unroll
            for (int u = 0; u < 4; ++u)
                #pragma unroll
                for (int q = 0; q < 4; ++q) {
                    acc[2 * q]     = fmaf(ex[u], __low2float(hv[u].h2[q]),  acc[2 * q]);
                    acc[2 * q + 1] = fmaf(ex[u], __high2float(hv[u].h2[q]), acc[2 * q + 1]);
                }
        }

        if (valid) {
            float inv = (deg > 0) ? 1.f / ssum : 0.f;
            float o[8];
            #pragma unroll
            for (int q = 0; q < 8; ++q) {
                float v = acc[q] * inv;
                o[q] = (v > 0.f) ? v : (__expf(v) - 1.f);
            }
            float4 o0 = {o[0], o[1], o[2], o[3]};
            float4 o1 = {o[4], o[5], o[6], o[7]};
            *(float4*)&out[(size_t)node * OUT_DIM + c8 * 8] = o0;
            *(float4*)&out[(size_t)node * OUT_DIM + c8 * 8 + 4] = o1;
        }
    }
}

// ===========================================================================
// Fallback path: proven 3-dispatch kernels (R13, passed @114us).
// ===========================================================================
__global__ __launch_bounds__(256) void fused_gp(
    const float* __restrict__ in, const float* __restrict__ W,
    const float* __restrict__ a, __half* __restrict__ hb,
    float* __restrict__ hs, float* __restrict__ hd,
    const int* __restrict__ src, const int* __restrict__ dst,
    int* __restrict__ gcursor, int* __restrict__ pairbuf,
    int E, int NBK, int PB, int N)
{
    __shared__ union {
        struct { _Float16 Al[GR][IN_DIM]; _Float16 Wt[OUT_DIM][IN_DIM + 8]; } g;
        struct { int lcount[MAXBK]; int lbase[MAXBK]; int lrun[MAXBK]; } p;
    } sm;

    const int t = threadIdx.x;

    if ((int)blockIdx.x < PB) {
        for (int i = t; i < NBK; i += 256) sm.p.lcount[i] = 0;
        __syncthreads();

        const int base = blockIdx.x * PA_CHUNK;
        int w[32];
        int nev = 0;
        #pragma unroll
        for (int j = 0; j < 8; ++j) {
            int i = base + j * 1024 + t * 4;
            if (i + 3 < E) {
                int4 s4 = *(const int4*)&src[i];
                int4 d4 = *(const int4*)&dst[i];
                int b0 = s4.x >> 5, b1 = s4.y >> 5, b2 = s4.z >> 5, b3 = s4.w >> 5;
                w[4 * j + 0] = (b0 << 21) | ((s4.x & 31) << 16) | d4.x;
                w[4 * j + 1] = (b1 << 21) | ((s4.y & 31) << 16) | d4.y;
                w[4 * j + 2] = (b2 << 21) | ((s4.z & 31) << 16) | d4.z;
                w[4 * j + 3] = (b3 << 21) | ((s4.w & 31) << 16) | d4.w;
                atomicAdd(&sm.p.lcount[b0], 1);
                atomicAdd(&sm.p.lcount[b1], 1);
                atomicAdd(&sm.p.lcount[b2], 1);
                atomicAdd(&sm.p.lcount[b3], 1);
                nev = 4 * j + 4;
            } else {
                #pragma unroll
                for (int u = 0; u < 4; ++u) {
                    if (i + u < E) {
                        int s = src[i + u];
                        int d = dst[i + u];
                        int bb = s >> 5;
                        w[4 * j + u] = (bb << 21) | ((s & 31) << 16) | d;
                        atomicAdd(&sm.p.lcount[bb], 1);
                        nev = 4 * j + u + 1;
                    }
                }
            }
        }
        __syncthreads();
        for (int i = t; i < NBK; i += 256) {
            int c = sm.p.lcount[i];
            int gb = 0;
            if (c > 0) gb = atomicAdd(&gcursor[i], c);
            sm.p.lbase[i] = i * CAP + gb;
            sm.p.lrun[i] = 0;
        }
        __syncthreads();
        #pragma unroll
        for (int k = 0; k < 32; ++k) {
            if (k < nev) {
                int bb = ((unsigned)w[k]) >> 21;
                int r = atomicAdd(&sm.p.lrun[bb], 1);
                int pos = sm.p.lbase[bb] + r;
                if (pos - bb * CAP < CAP)
                    pairbuf[pos] = w[k];
            }
        }
        return;
    }

    const int r0 = (blockIdx.x - PB) * GR;

    #pragma unroll
    for (int i = 0; i < 8; ++i) {
        int q = i * 256 + t;
        int row = q >> 5;
        int kq  = (q & 31) * 4;
        int grow = r0 + row; if (grow >= N) grow = N - 1;
        float4 v = *(const float4*)&in[(size_t)grow * IN_DIM + kq];
        union { __half2 h2[2]; uint2 u; } cv;
        cv.h2[0] = __floats2half2_rn(v.x, v.y);
        cv.h2[1] = __floats2half2_rn(v.z, v.w);
        *(uint2*)&sm.g.Al[row][kq] = cv.u;
    }
    #pragma unroll
    for (int i = 0; i < 8; ++i) {
        int q = i * 256 + t;
        int k  = q >> 4;
        int n4 = (q & 15) * 4;
        float4 v = *(const float4*)&W[(size_t)k * OUT_DIM + n4];
        sm.g.Wt[n4 + 0][k] = (_Float16)v.x;
        sm.g.Wt[n4 + 1][k] = (_Float16)v.y;
        sm.g.Wt[n4 + 2][k] = (_Float16)v.z;
        sm.g.Wt[n4 + 3][k] = (_Float16)v.w;
    }
    __syncthreads();

    const int lane = t & 63;
    const int wave = t >> 6;
    const int m16  = lane & 15;
    const int quad = lane >> 4;

    floatx4 acc[4];
    #pragma unroll
    for (int nt = 0; nt < 4; ++nt) acc[nt] = (floatx4){0.f, 0.f, 0.f, 0.f};

    #pragma unroll
    for (int kc = 0; kc < 4; ++kc) {
        half8 af = *(const half8*)&sm.g.Al[wave * 16 + m16][kc * 32 + quad * 8];
        #pragma unroll
        for (int nt = 0; nt < 4; ++nt) {
            half8 bf = *(const half8*)&sm.g.Wt[nt * 16 + m16][kc * 32 + quad * 8];
            acc[nt] = __builtin_amdgcn_mfma_f32_16x16x32_f16(af, bf, acc[nt], 0, 0, 0);
        }
    }
    __syncthreads();

    _Float16 (*Crep)[OUT_DIM + 8] = (_Float16(*)[OUT_DIM + 8])&sm.g.Al[0][0];

    float asl[4], adl[4];
    #pragma unroll
    for (int nt = 0; nt < 4; ++nt) {
        asl[nt] = a[nt * 16 + m16];
        adl[nt] = a[OUT_DIM + nt * 16 + m16];
    }
    #pragma unroll
    for (int r = 0; r < 4; ++r) {
        float ps = 0.f, pd = 0.f;
        #pragma unroll
        for (int nt = 0; nt < 4; ++nt) {
            ps = fmaf(acc[nt][r], asl[nt], ps);
            pd = fmaf(acc[nt][r], adl[nt], pd);
        }
        #pragma unroll
        for (int off = 1; off < 16; off <<= 1) {
            ps += __shfl_xor(ps, off, 64);
            pd += __shfl_xor(pd, off, 64);
        }
        if (m16 == 0) {
            int row = r0 + wave * 16 + quad * 4 + r;
            if (row < N) { hs[row] = ps; hd[row] = pd; }
        }
    }

    #pragma unroll
    for (int nt = 0; nt < 4; ++nt)
        #pragma unroll
        for (int r = 0; r < 4; ++r)
            Crep[wave * 16 + quad * 4 + r][nt * 16 + m16] = (_Float16)acc[nt][r];
    __syncthreads();
    #pragma unroll
    for (int i = 0; i < 2; ++i) {
        int idx = i * 256 + t;
        int row = idx >> 3;
        int seg = idx & 7;
        int gr2 = r0 + row;
        if (gr2 < N) {
            uint4 v = *(const uint4*)&Crep[row][seg * 8];
            *(uint4*)&hb[(size_t)gr2 * OUT_DIM + seg * 8] = v;
        }
    }
}

__global__ __launch_bounds__(256) void node_kernel(
    const __half* __restrict__ hb, const float* __restrict__ hs,
    const float* __restrict__ hd, const int* __restrict__ gcursor,
    const int* __restrict__ pairbuf, float* __restrict__ out, int N)
{
    __shared__ int2  spair[CAP];
    __shared__ float hsl[BUCKET_SRCS];
    __shared__ int   cnt[BUCKET_SRCS];
    __shared__ int   excl[BUCKET_SRCS];
    __shared__ int   lcur[BUCKET_SRCS];
    __shared__ int   perm[BUCKET_SRCS];

    const int t = threadIdx.x;
    const int b = blockIdx.x;
    const int M = min(gcursor[b], CAP);

    if (t < BUCKET_SRCS) {
        int node = b * BUCKET_SRCS + t;
        hsl[t] = (node < N) ? hs[node] : 0.f;
        cnt[t] = 0;
    }
    __syncthreads();

    const int i0 = t * 4;
    int4 p4 = *(const int4*)&pairbuf[b * CAP + i0];
    int   pkv[4] = {p4.x, p4.y, p4.z, p4.w};
    int   dofs[4], slv[4];
    float exv[4];
    int nl = 0;
    #pragma unroll
    for (int u = 0; u < 4; ++u) {
        if (i0 + u < M) {
            int pk = pkv[u];
            int sl = (pk >> 16) & 31;
            int d  = pk & 0xffff;
            float e = hsl[sl] + hd[d];
            e = (e >= 0.f) ? e : NEG_SLOPE * e;
            exv[u]  = __expf(e);
            slv[u]  = sl;
            dofs[u] = d << 7;
            atomicAdd(&cnt[sl], 1);
            nl = u + 1;
        }
    }
    __syncthreads();
    if (t < BUCKET_SRCS) {
        int raw = cnt[t];
        int v = raw;
        #pragma unroll
        for (int off = 1; off < BUCKET_SRCS; off <<= 1) {
            int u = __shfl_up(v, off, 64);
            if (t >= off) v += u;
        }
        excl[t] = v - raw;
        lcur[t] = v - raw;

        int key = raw * 32 + t;
        #pragma unroll
        for (int k = 2; k <= 32; k <<= 1) {
            #pragma unroll
            for (int j = k >> 1; j > 0; j >>= 1) {
                int other = __shfl_xor(key, j, 64);
                bool up = (t & k) == 0;
                bool lower = (t & j) == 0;
                int mn = min(key, other), mx = max(key, other);
                key = (up == lower) ? mn : mx;
            }
        }
        perm[t] = key & 31;
    }
    __syncthreads();
    #pragma unroll
    for (int u = 0; u < 4; ++u) {
        if (u < nl) {
            int r = atomicAdd(&lcur[slv[u]], 1);
            spair[r] = make_int2(__float_as_int(exv[u]), dofs[u]);
        }
    }
    __syncthreads();

    const int lane = t & 63;
    const int wave = t >> 6;
    const int slot = lane >> 3;
    const int c8   = lane & 7;
    const int loc  = perm[wave * 8 + slot];
    const int node = b * BUCKET_SRCS + loc;
    const bool valid = node < N;

    const int deg = cnt[loc];
    const int beg = excl[loc];

    int dmax = deg;
    #pragma unroll
    for (int off = 8; off < 64; off <<= 1)
        dmax = max(dmax, __shfl_xor(dmax, off, 64));

    const char* hbp = (const char*)hb + c8 * 16;

    float acc[8];
    float ssum = 0.f;
    #pragma unroll
    for (int q = 0; q < 8; ++q) acc[q] = 0.f;

    for (int j = 0; j < dmax; j += 4) {
        int2 pr[4];
        float ex[4];
        #pragma unroll
        for (int u = 0; u < 4; ++u) {
            bool act = j + u < deg;
            pr[u] = spair[beg + (act ? j + u : 0)];
            ex[u] = act ? __int_as_float(pr[u].x) : 0.f;
            ssum += ex[u];
        }
        union { uint4 u4; __half2 h2[4]; } hv[4];
        #pragma unroll
        for (int u = 0; u < 4; ++u)
            hv[u].u4 = *(const uint4*)(hbp + pr[u].y);
        #pragma unroll
        for (int u = 0; u < 4; ++u)
            #pragma unroll
            for (int q = 0; q < 4; ++q) {
                acc[2 * q]     = fmaf(ex[u], __low2float(hv[u].h2[q]),  acc[2 * q]);
                acc[2 * q + 1] = fmaf(ex[u], __high2float(hv[u].h2[q]), acc[2 * q + 1]);
            }
    }

    if (valid) {
        float inv = (deg > 0) ? 1.f / ssum : 0.f;
        float o[8];
        #pragma unroll
        for (int q = 0; q < 8; ++q) {
            float v = acc[q] * inv;
            o[q] = (v > 0.f) ? v : (__expf(v) - 1.f);
        }
        float4 o0 = {o[0], o[1], o[2], o[3]};
        float4 o1 = {o[4], o[5], o[6], o[7]};
        *(float4*)&out[(size_t)node * OUT_DIM + c8 * 8] = o0;
        *(float4*)&out[(size_t)node * OUT_DIM + c8 * 8 + 4] = o1;
    }
}

// ---------------------------------------------------------------------------
extern "C" void kernel_launch(void* const* d_in, const int* in_sizes, int n_in,
                              void* d_out, int out_size, void* d_ws, size_t ws_size,
                              hipStream_t stream)
{
    const float* input = (const float*)d_in[0];
    const int*   edge  = (const int*)d_in[1];
    const float* W     = (const float*)d_in[2];
    const float* a     = (const float*)d_in[3];
    float* out = (float*)d_out;

    const int N = in_sizes[0] / IN_DIM;
    const int E = in_sizes[1] / 2;
    const int* srcp = edge;
    const int* dstp = edge + E;

    const int NBK = (N + BUCKET_SRCS - 1) / BUCKET_SRCS;   // 1563
    const int PB  = (E + PA_CHUNK - 1) / PA_CHUNK;         // 98
    const int GB  = (N + GR - 1) / GR;                     // 782
    int NITEM = PB + GB;                                   // 880

    size_t idx = 0;
    int* gcursor = (int*)d_ws + idx; idx += MAXBK;
    int* pairbuf = (int*)d_ws + idx; idx += (size_t)NBK * CAP;
    __half* hb = (__half*)((int*)d_ws + idx); idx += (size_t)N * OUT_DIM / 2;
    float* hs = (float*)((int*)d_ws + idx); idx += N;
    float* hd = (float*)((int*)d_ws + idx); idx += N;

    // ---- cooperative-launch viability, queried once ----------------------
    static int coop_blocks = -1;          // -1 = unknown, 0 = disabled
    if (coop_blocks < 0) {
        int bpc = 0;
        hipError_t e = hipOccupancyMaxActiveBlocksPerMultiprocessor(
            &bpc, gat_all, 256, 0);
        if (e == hipSuccess && bpc >= 1) {
            coop_blocks = bpc * 256;      // 256 CUs on MI355X
            if (coop_blocks > 1024) coop_blocks = 1024;
        } else {
            coop_blocks = 0;
        }
    }

    bool done = false;
    if (coop_blocks >= 256) {
        void* args[] = { (void*)&input, (void*)&W, (void*)&a, (void*)&hb,
                         (void*)&hs, (void*)&hd, (void*)&srcp, (void*)&dstp,
                         (void*)&gcursor, (void*)&pairbuf, (void*)&out,
                         (void*)&E, (void*)&NBK, (void*)&PB, (void*)&NITEM,
                         (void*)&N };
        hipError_t e = hipLaunchCooperativeKernel(
            (const void*)gat_all, dim3(coop_blocks), dim3(256), args, 0, stream);
        if (e == hipSuccess) {
            done = true;
        } else {
            coop_blocks = 0;              // never retry; use fallback forever
        }
    }

    if (!done) {
        hipMemsetAsync(gcursor, 0, MAXBK * sizeof(int), stream);
        fused_gp<<<PB + GB, 256, 0, stream>>>(
            input, W, a, hb, hs, hd, srcp, dstp, gcursor, pairbuf, E, NBK, PB, N);
        node_kernel<<<NBK, 256, 0, stream>>>(hb, hs, hd, gcursor, pairbuf, out, N);
    }
}

// Round 4
// 116.167 us; speedup vs baseline: 2.1875x; 2.1875x over previous
//
#include <hip/hip_runtime.h>
#include <hip/hip_fp16.h>
#include <math.h>

#define IN_DIM 128
#define OUT_DIM 64
#define NEG_SLOPE 0.2f

// Bucket = 32 consecutive src ids. CAP = 1024 edges/bucket (mean 512 for
// E=800K,N=50K). N < 65536 so dst fits 16 bits in the packed word.
#define BUCKET_SRCS 32
#define CAP 1024
#define MAXBK 2048

typedef _Float16 half8 __attribute__((ext_vector_type(8)));
typedef float floatx4 __attribute__((ext_vector_type(4)));

#define GR 64
#define PA_CHUNK 8192

// R16: coop single-kernel path removed (R15: 2.2x slower — LDS union cut
// phase-B occupancy to 4 blocks/CU; workload is latency-bound per counters:
// Occupancy 35%, VALUBusy 2.4%, HBM 3%). Back to the proven 3-dispatch
// structure; the new lever is MLP in node_kernel's gather loop.
// ---------------------------------------------------------------------------
__global__ __launch_bounds__(256) void fused_gp(
    const float* __restrict__ in, const float* __restrict__ W,
    const float* __restrict__ a, __half* __restrict__ hb,
    float* __restrict__ hs, float* __restrict__ hd,
    const int* __restrict__ src, const int* __restrict__ dst,
    int* __restrict__ gcursor, int* __restrict__ pairbuf,
    int E, int NBK, int PB, int N)
{
    __shared__ union {
        struct { _Float16 Al[GR][IN_DIM]; _Float16 Wt[OUT_DIM][IN_DIM + 8]; } g;
        struct { int lcount[MAXBK]; int lbase[MAXBK]; int lrun[MAXBK]; } p;
    } sm;

    const int t = threadIdx.x;

    if ((int)blockIdx.x < PB) {
        // ----------------------- partition phase ---------------------------
        for (int i = t; i < NBK; i += 256) sm.p.lcount[i] = 0;
        __syncthreads();

        const int base = blockIdx.x * PA_CHUNK;
        int w[32];
        int nev = 0;
        #pragma unroll
        for (int j = 0; j < 8; ++j) {
            int i = base + j * 1024 + t * 4;
            if (i + 3 < E) {
                int4 s4 = *(const int4*)&src[i];
                int4 d4 = *(const int4*)&dst[i];
                int b0 = s4.x >> 5, b1 = s4.y >> 5, b2 = s4.z >> 5, b3 = s4.w >> 5;
                w[4 * j + 0] = (b0 << 21) | ((s4.x & 31) << 16) | d4.x;
                w[4 * j + 1] = (b1 << 21) | ((s4.y & 31) << 16) | d4.y;
                w[4 * j + 2] = (b2 << 21) | ((s4.z & 31) << 16) | d4.z;
                w[4 * j + 3] = (b3 << 21) | ((s4.w & 31) << 16) | d4.w;
                atomicAdd(&sm.p.lcount[b0], 1);
                atomicAdd(&sm.p.lcount[b1], 1);
                atomicAdd(&sm.p.lcount[b2], 1);
                atomicAdd(&sm.p.lcount[b3], 1);
                nev = 4 * j + 4;
            } else {
                #pragma unroll
                for (int u = 0; u < 4; ++u) {
                    if (i + u < E) {
                        int s = src[i + u];
                        int d = dst[i + u];
                        int bb = s >> 5;
                        w[4 * j + u] = (bb << 21) | ((s & 31) << 16) | d;
                        atomicAdd(&sm.p.lcount[bb], 1);
                        nev = 4 * j + u + 1;
                    }
                }
            }
        }
        __syncthreads();
        for (int i = t; i < NBK; i += 256) {
            int c = sm.p.lcount[i];
            int gb = 0;
            if (c > 0) gb = atomicAdd(&gcursor[i], c);
            sm.p.lbase[i] = i * CAP + gb;
            sm.p.lrun[i] = 0;
        }
        __syncthreads();
        #pragma unroll
        for (int k = 0; k < 32; ++k) {
            if (k < nev) {
                int bb = ((unsigned)w[k]) >> 21;
                int r = atomicAdd(&sm.p.lrun[bb], 1);
                int pos = sm.p.lbase[bb] + r;
                if (pos - bb * CAP < CAP)     // capacity guard (memory safety)
                    pairbuf[pos] = w[k];
            }
        }
        return;
    }

    // ------------------------- gemm phase ----------------------------------
    const int r0 = (blockIdx.x - PB) * GR;

    #pragma unroll
    for (int i = 0; i < 8; ++i) {
        int q = i * 256 + t;
        int row = q >> 5;
        int kq  = (q & 31) * 4;
        int grow = r0 + row; if (grow >= N) grow = N - 1;
        float4 v = *(const float4*)&in[(size_t)grow * IN_DIM + kq];
        union { __half2 h2[2]; uint2 u; } cv;
        cv.h2[0] = __floats2half2_rn(v.x, v.y);
        cv.h2[1] = __floats2half2_rn(v.z, v.w);
        *(uint2*)&sm.g.Al[row][kq] = cv.u;
    }
    #pragma unroll
    for (int i = 0; i < 8; ++i) {
        int q = i * 256 + t;
        int k  = q >> 4;
        int n4 = (q & 15) * 4;
        float4 v = *(const float4*)&W[(size_t)k * OUT_DIM + n4];
        sm.g.Wt[n4 + 0][k] = (_Float16)v.x;
        sm.g.Wt[n4 + 1][k] = (_Float16)v.y;
        sm.g.Wt[n4 + 2][k] = (_Float16)v.z;
        sm.g.Wt[n4 + 3][k] = (_Float16)v.w;
    }
    __syncthreads();

    const int lane = t & 63;
    const int wave = t >> 6;
    const int m16  = lane & 15;
    const int quad = lane >> 4;

    floatx4 acc[4];
    #pragma unroll
    for (int nt = 0; nt < 4; ++nt) acc[nt] = (floatx4){0.f, 0.f, 0.f, 0.f};

    #pragma unroll
    for (int kc = 0; kc < 4; ++kc) {
        half8 af = *(const half8*)&sm.g.Al[wave * 16 + m16][kc * 32 + quad * 8];
        #pragma unroll
        for (int nt = 0; nt < 4; ++nt) {
            half8 bf = *(const half8*)&sm.g.Wt[nt * 16 + m16][kc * 32 + quad * 8];
            acc[nt] = __builtin_amdgcn_mfma_f32_16x16x32_f16(af, bf, acc[nt], 0, 0, 0);
        }
    }
    __syncthreads();   // Al dead from here; Crep aliases it

    _Float16 (*Crep)[OUT_DIM + 8] = (_Float16(*)[OUT_DIM + 8])&sm.g.Al[0][0];

    float asl[4], adl[4];
    #pragma unroll
    for (int nt = 0; nt < 4; ++nt) {
        asl[nt] = a[nt * 16 + m16];
        adl[nt] = a[OUT_DIM + nt * 16 + m16];
    }
    #pragma unroll
    for (int r = 0; r < 4; ++r) {
        float ps = 0.f, pd = 0.f;
        #pragma unroll
        for (int nt = 0; nt < 4; ++nt) {
            ps = fmaf(acc[nt][r], asl[nt], ps);
            pd = fmaf(acc[nt][r], adl[nt], pd);
        }
        #pragma unroll
        for (int off = 1; off < 16; off <<= 1) {
            ps += __shfl_xor(ps, off, 64);
            pd += __shfl_xor(pd, off, 64);
        }
        if (m16 == 0) {
            int row = r0 + wave * 16 + quad * 4 + r;
            if (row < N) { hs[row] = ps; hd[row] = pd; }
        }
    }

    #pragma unroll
    for (int nt = 0; nt < 4; ++nt)
        #pragma unroll
        for (int r = 0; r < 4; ++r)
            Crep[wave * 16 + quad * 4 + r][nt * 16 + m16] = (_Float16)acc[nt][r];
    __syncthreads();
    #pragma unroll
    for (int i = 0; i < 2; ++i) {
        int idx = i * 256 + t;
        int row = idx >> 3;
        int seg = idx & 7;
        int gr2 = r0 + row;
        if (gr2 < N) {
            uint4 v = *(const uint4*)&Crep[row][seg * 8];
            *(uint4*)&hb[(size_t)gr2 * OUT_DIM + seg * 8] = v;
        }
    }
}

// ---------------------------------------------------------------------------
// Kernel 3: one block per bucket (32 nodes).
// R16: phase 2 gather loop is 2-stage software-pipelined — issue iteration
// j+4's four uint4 gathers BEFORE the FMA block of iteration j, so the FMA
// waitcnt is vmcnt(4) not vmcnt(0): 8 loads in flight/thread (was 4).
// The gather is the latency-critical path (800K random 128B hb rows).
// ---------------------------------------------------------------------------
__global__ __launch_bounds__(256) void node_kernel(
    const __half* __restrict__ hb, const float* __restrict__ hs,
    const float* __restrict__ hd, const int* __restrict__ gcursor,
    const int* __restrict__ pairbuf, float* __restrict__ out, int N)
{
    __shared__ int2  spair[CAP];
    __shared__ float hsl[BUCKET_SRCS];
    __shared__ int   cnt[BUCKET_SRCS];
    __shared__ int   excl[BUCKET_SRCS];
    __shared__ int   lcur[BUCKET_SRCS];
    __shared__ int   perm[BUCKET_SRCS];

    const int t = threadIdx.x;
    const int b = blockIdx.x;
    const int M = min(gcursor[b], CAP);

    if (t < BUCKET_SRCS) {
        int node = b * BUCKET_SRCS + t;
        hsl[t] = (node < N) ? hs[node] : 0.f;
        cnt[t] = 0;
    }
    __syncthreads();

    const int i0 = t * 4;
    int4 p4 = *(const int4*)&pairbuf[b * CAP + i0];
    int   pkv[4] = {p4.x, p4.y, p4.z, p4.w};
    int   dofs[4], slv[4];
    float exv[4];
    int nl = 0;
    #pragma unroll
    for (int u = 0; u < 4; ++u) {
        if (i0 + u < M) {
            int pk = pkv[u];
            int sl = (pk >> 16) & 31;
            int d  = pk & 0xffff;
            float e = hsl[sl] + hd[d];
            e = (e >= 0.f) ? e : NEG_SLOPE * e;
            exv[u]  = __expf(e);
            slv[u]  = sl;
            dofs[u] = d << 7;                 // byte offset: d * OUT_DIM * 2
            atomicAdd(&cnt[sl], 1);
            nl = u + 1;
        }
    }
    __syncthreads();
    if (t < BUCKET_SRCS) {
        int raw = cnt[t];
        int v = raw;
        #pragma unroll
        for (int off = 1; off < BUCKET_SRCS; off <<= 1) {
            int u = __shfl_up(v, off, 64);
            if (t >= off) v += u;
        }
        excl[t] = v - raw;
        lcur[t] = v - raw;

        // bitonic sort (ascending) of key = deg*32 + idx across lanes 0..31
        int key = raw * 32 + t;
        #pragma unroll
        for (int k = 2; k <= 32; k <<= 1) {
            #pragma unroll
            for (int j = k >> 1; j > 0; j >>= 1) {
                int other = __shfl_xor(key, j, 64);
                bool up = (t & k) == 0;
                bool lower = (t & j) == 0;
                int mn = min(key, other), mx = max(key, other);
                key = (up == lower) ? mn : mx;
            }
        }
        perm[t] = key & 31;     // rank t -> original node-local index
    }
    __syncthreads();
    #pragma unroll
    for (int u = 0; u < 4; ++u) {
        if (u < nl) {
            int r = atomicAdd(&lcur[slv[u]], 1);
            spair[r] = make_int2(__float_as_int(exv[u]), dofs[u]);
        }
    }
    __syncthreads();

    // phase 2: slot = node (degree-balanced via perm)
    const int lane = t & 63;
    const int wave = t >> 6;
    const int slot = lane >> 3;
    const int c8   = lane & 7;
    const int loc  = perm[wave * 8 + slot];
    const int node = b * BUCKET_SRCS + loc;
    const bool valid = node < N;

    const int deg = cnt[loc];
    const int beg = excl[loc];

    int dmax = deg;
    #pragma unroll
    for (int off = 8; off < 64; off <<= 1)
        dmax = max(dmax, __shfl_xor(dmax, off, 64));

    const char* hbp = (const char*)hb + c8 * 16;   // lane-constant base

    float acc[8];
    float ssum = 0.f;
    #pragma unroll
    for (int q = 0; q < 8; ++q) acc[q] = 0.f;

    // ---- 2-stage pipelined gather loop --------------------------------
    int2  pr[4];  float ex[4];
    union { uint4 u4; __half2 h2[4]; } hv[4];

    // prologue: stage j=0 (spair read + issue gathers)
    #pragma unroll
    for (int u = 0; u < 4; ++u) {
        bool act = u < deg;
        int idx = min(beg + (act ? u : 0), CAP - 1);
        pr[u] = spair[idx];
        ex[u] = act ? __int_as_float(pr[u].x) : 0.f;
    }
    #pragma unroll
    for (int u = 0; u < 4; ++u)
        hv[u].u4 = *(const uint4*)(hbp + pr[u].y);

    for (int j = 0; j < dmax; j += 4) {
        // prefetch stage j+4: spair reads + ISSUE gathers (independent regs)
        int2  prn[4]; float exn[4];
        union { uint4 u4; __half2 h2[4]; } hvn[4];
        const int jn = j + 4;
        if (jn < dmax) {
            #pragma unroll
            for (int u = 0; u < 4; ++u) {
                bool act = jn + u < deg;
                int idx = min(beg + (act ? jn + u : 0), CAP - 1);
                prn[u] = spair[idx];
                exn[u] = act ? __int_as_float(prn[u].x) : 0.f;
            }
            #pragma unroll
            for (int u = 0; u < 4; ++u)
                hvn[u].u4 = *(const uint4*)(hbp + prn[u].y);
        } else {
            #pragma unroll
            for (int u = 0; u < 4; ++u) { exn[u] = 0.f; hvn[u].u4 = hv[u].u4; }
        }

        // compute stage j (waits vmcnt(4), not vmcnt(0))
        #pragma unroll
        for (int u = 0; u < 4; ++u) {
            ssum += ex[u];
            #pragma unroll
            for (int q = 0; q < 4; ++q) {
                acc[2 * q]     = fmaf(ex[u], __low2float(hv[u].h2[q]),  acc[2 * q]);
                acc[2 * q + 1] = fmaf(ex[u], __high2float(hv[u].h2[q]), acc[2 * q + 1]);
            }
        }

        // rotate
        #pragma unroll
        for (int u = 0; u < 4; ++u) { ex[u] = exn[u]; hv[u].u4 = hvn[u].u4; }
    }

    if (valid) {
        float inv = (deg > 0) ? 1.f / ssum : 0.f;
        float o[8];
        #pragma unroll
        for (int q = 0; q < 8; ++q) {
            float v = acc[q] * inv;
            o[q] = (v > 0.f) ? v : (__expf(v) - 1.f);
        }
        float4 o0 = {o[0], o[1], o[2], o[3]};
        float4 o1 = {o[4], o[5], o[6], o[7]};
        *(float4*)&out[(size_t)node * OUT_DIM + c8 * 8] = o0;
        *(float4*)&out[(size_t)node * OUT_DIM + c8 * 8 + 4] = o1;
    }
}

// ---------------------------------------------------------------------------
extern "C" void kernel_launch(void* const* d_in, const int* in_sizes, int n_in,
                              void* d_out, int out_size, void* d_ws, size_t ws_size,
                              hipStream_t stream)
{
    const float* input = (const float*)d_in[0];
    const int*   edge  = (const int*)d_in[1];
    const float* W     = (const float*)d_in[2];
    const float* a     = (const float*)d_in[3];
    float* out = (float*)d_out;

    const int N = in_sizes[0] / IN_DIM;
    const int E = in_sizes[1] / 2;
    const int* src = edge;
    const int* dst = edge + E;

    const int NBK = (N + BUCKET_SRCS - 1) / BUCKET_SRCS;   // 1563
    const int PB  = (E + PA_CHUNK - 1) / PA_CHUNK;         // 98
    const int GB  = (N + GR - 1) / GR;                     // 782

    size_t idx = 0;
    int* gcursor = (int*)d_ws + idx; idx += MAXBK;
    int* pairbuf = (int*)d_ws + idx; idx += (size_t)NBK * CAP;
    __half* hb = (__half*)((int*)d_ws + idx); idx += (size_t)N * OUT_DIM / 2;
    float* hs = (float*)((int*)d_ws + idx); idx += N;
    float* hd = (float*)((int*)d_ws + idx); idx += N;

    hipMemsetAsync(gcursor, 0, MAXBK * sizeof(int), stream);
    fused_gp<<<PB + GB, 256, 0, stream>>>(
        input, W, a, hb, hs, hd, src, dst, gcursor, pairbuf, E, NBK, PB, N);
    node_kernel<<<NBK, 256, 0, stream>>>(hb, hs, hd, gcursor, pairbuf, out, N);
}

// Round 5
// 115.965 us; speedup vs baseline: 2.1913x; 1.0017x over previous
//
#include <hip/hip_runtime.h>
#include <hip/hip_fp16.h>
#include <math.h>

#define IN_DIM 128
#define OUT_DIM 64
#define NEG_SLOPE 0.2f

// Bucket = 32 consecutive src ids. CAP = 1024 edges/bucket (mean 512 for
// E=800K,N=50K). N < 65536 so dst fits 16 bits in the packed word.
#define BUCKET_SRCS 32
#define CAP 1024
#define MAXBK 2048

typedef _Float16 half8 __attribute__((ext_vector_type(8)));
typedef float floatx4 __attribute__((ext_vector_type(4)));

#define GR 64
#define PA_CHUNK 8192

// ---------------------------------------------------------------------------
// R17: init_kernel replaces the hipMemsetAsync dispatch (1:1). It zeroes
// gcursor AND pre-transposes W into fp16 Wt_g[64][128] in workspace, so each
// of the 782 gemm blocks stages Wt with 4 coalesced uint4 loads + 4 vector
// LDS stores per thread instead of 8 float4 loads + 16 cvts + 32 scalar
// strided LDS stores. Same fp16 values reach the MFMA (identical rounding).
// ---------------------------------------------------------------------------
__global__ __launch_bounds__(256) void init_kernel(
    const float* __restrict__ W, int* __restrict__ gcursor,
    __half* __restrict__ Wt_g)
{
    const int id = blockIdx.x * 256 + threadIdx.x;
    if (id < MAXBK) gcursor[id] = 0;
    if (id < OUT_DIM * IN_DIM) {
        int n = id >> 7;            // output col (0..63)
        int k = id & 127;           // input dim  (0..127)
        Wt_g[id] = (__half)W[k * OUT_DIM + n];   // Wt_g[n][k] = W[k][n]
    }
}

// ---------------------------------------------------------------------------
// Fused kernel: partition blocks FIRST, gemm blocks after. (R16 structure;
// only the Wt staging path changed — now reads pre-transposed fp16 Wt_g.)
// ---------------------------------------------------------------------------
__global__ __launch_bounds__(256) void fused_gp(
    const float* __restrict__ in, const __half* __restrict__ Wt_g,
    const float* __restrict__ a, __half* __restrict__ hb,
    float* __restrict__ hs, float* __restrict__ hd,
    const int* __restrict__ src, const int* __restrict__ dst,
    int* __restrict__ gcursor, int* __restrict__ pairbuf,
    int E, int NBK, int PB, int N)
{
    __shared__ union {
        struct { _Float16 Al[GR][IN_DIM]; _Float16 Wt[OUT_DIM][IN_DIM + 8]; } g;
        struct { int lcount[MAXBK]; int lbase[MAXBK]; int lrun[MAXBK]; } p;
    } sm;

    const int t = threadIdx.x;

    if ((int)blockIdx.x < PB) {
        // ----------------------- partition phase ---------------------------
        for (int i = t; i < NBK; i += 256) sm.p.lcount[i] = 0;
        __syncthreads();

        const int base = blockIdx.x * PA_CHUNK;
        int w[32];
        int nev = 0;
        #pragma unroll
        for (int j = 0; j < 8; ++j) {
            int i = base + j * 1024 + t * 4;
            if (i + 3 < E) {
                int4 s4 = *(const int4*)&src[i];
                int4 d4 = *(const int4*)&dst[i];
                int b0 = s4.x >> 5, b1 = s4.y >> 5, b2 = s4.z >> 5, b3 = s4.w >> 5;
                w[4 * j + 0] = (b0 << 21) | ((s4.x & 31) << 16) | d4.x;
                w[4 * j + 1] = (b1 << 21) | ((s4.y & 31) << 16) | d4.y;
                w[4 * j + 2] = (b2 << 21) | ((s4.z & 31) << 16) | d4.z;
                w[4 * j + 3] = (b3 << 21) | ((s4.w & 31) << 16) | d4.w;
                atomicAdd(&sm.p.lcount[b0], 1);
                atomicAdd(&sm.p.lcount[b1], 1);
                atomicAdd(&sm.p.lcount[b2], 1);
                atomicAdd(&sm.p.lcount[b3], 1);
                nev = 4 * j + 4;
            } else {
                #pragma unroll
                for (int u = 0; u < 4; ++u) {
                    if (i + u < E) {
                        int s = src[i + u];
                        int d = dst[i + u];
                        int bb = s >> 5;
                        w[4 * j + u] = (bb << 21) | ((s & 31) << 16) | d;
                        atomicAdd(&sm.p.lcount[bb], 1);
                        nev = 4 * j + u + 1;
                    }
                }
            }
        }
        __syncthreads();
        for (int i = t; i < NBK; i += 256) {
            int c = sm.p.lcount[i];
            int gb = 0;
            if (c > 0) gb = atomicAdd(&gcursor[i], c);
            sm.p.lbase[i] = i * CAP + gb;
            sm.p.lrun[i] = 0;
        }
        __syncthreads();
        #pragma unroll
        for (int k = 0; k < 32; ++k) {
            if (k < nev) {
                int bb = ((unsigned)w[k]) >> 21;
                int r = atomicAdd(&sm.p.lrun[bb], 1);
                int pos = sm.p.lbase[bb] + r;
                if (pos - bb * CAP < CAP)     // capacity guard (memory safety)
                    pairbuf[pos] = w[k];
            }
        }
        return;
    }

    // ------------------------- gemm phase ----------------------------------
    const int r0 = (blockIdx.x - PB) * GR;

    #pragma unroll
    for (int i = 0; i < 8; ++i) {
        int q = i * 256 + t;
        int row = q >> 5;
        int kq  = (q & 31) * 4;
        int grow = r0 + row; if (grow >= N) grow = N - 1;
        float4 v = *(const float4*)&in[(size_t)grow * IN_DIM + kq];
        union { __half2 h2[2]; uint2 u; } cv;
        cv.h2[0] = __floats2half2_rn(v.x, v.y);
        cv.h2[1] = __floats2half2_rn(v.z, v.w);
        *(uint2*)&sm.g.Al[row][kq] = cv.u;
    }
    // Wt staging: pre-transposed fp16 from global — 4 uint4 loads + 4 vector
    // LDS stores per thread (was 8 float4 loads + cvts + 32 scalar stores).
    {
        const uint4* Wg4 = (const uint4*)Wt_g;       // 1024 uint4; 16 per row
        #pragma unroll
        for (int i = 0; i < 4; ++i) {
            int idx = i * 256 + t;                   // [0,1024)
            int n  = idx >> 4;                       // row (0..63)
            int c8 = (idx & 15) * 8;                 // col start (halves)
            uint4 v = Wg4[idx];
            *(uint4*)&sm.g.Wt[n][c8] = v;
        }
    }
    __syncthreads();

    const int lane = t & 63;
    const int wave = t >> 6;
    const int m16  = lane & 15;
    const int quad = lane >> 4;

    floatx4 acc[4];
    #pragma unroll
    for (int nt = 0; nt < 4; ++nt) acc[nt] = (floatx4){0.f, 0.f, 0.f, 0.f};

    #pragma unroll
    for (int kc = 0; kc < 4; ++kc) {
        half8 af = *(const half8*)&sm.g.Al[wave * 16 + m16][kc * 32 + quad * 8];
        #pragma unroll
        for (int nt = 0; nt < 4; ++nt) {
            half8 bf = *(const half8*)&sm.g.Wt[nt * 16 + m16][kc * 32 + quad * 8];
            acc[nt] = __builtin_amdgcn_mfma_f32_16x16x32_f16(af, bf, acc[nt], 0, 0, 0);
        }
    }
    __syncthreads();   // Al dead from here; Crep aliases it

    _Float16 (*Crep)[OUT_DIM + 8] = (_Float16(*)[OUT_DIM + 8])&sm.g.Al[0][0];

    float asl[4], adl[4];
    #pragma unroll
    for (int nt = 0; nt < 4; ++nt) {
        asl[nt] = a[nt * 16 + m16];
        adl[nt] = a[OUT_DIM + nt * 16 + m16];
    }
    #pragma unroll
    for (int r = 0; r < 4; ++r) {
        float ps = 0.f, pd = 0.f;
        #pragma unroll
        for (int nt = 0; nt < 4; ++nt) {
            ps = fmaf(acc[nt][r], asl[nt], ps);
            pd = fmaf(acc[nt][r], adl[nt], pd);
        }
        #pragma unroll
        for (int off = 1; off < 16; off <<= 1) {
            ps += __shfl_xor(ps, off, 64);
            pd += __shfl_xor(pd, off, 64);
        }
        if (m16 == 0) {
            int row = r0 + wave * 16 + quad * 4 + r;
            if (row < N) { hs[row] = ps; hd[row] = pd; }
        }
    }

    #pragma unroll
    for (int nt = 0; nt < 4; ++nt)
        #pragma unroll
        for (int r = 0; r < 4; ++r)
            Crep[wave * 16 + quad * 4 + r][nt * 16 + m16] = (_Float16)acc[nt][r];
    __syncthreads();
    #pragma unroll
    for (int i = 0; i < 2; ++i) {
        int idx = i * 256 + t;
        int row = idx >> 3;
        int seg = idx & 7;
        int gr2 = r0 + row;
        if (gr2 < N) {
            uint4 v = *(const uint4*)&Crep[row][seg * 8];
            *(uint4*)&hb[(size_t)gr2 * OUT_DIM + seg * 8] = v;
        }
    }
}

// ---------------------------------------------------------------------------
// Kernel 3: one block per bucket (32 nodes). Byte-identical to R16 (passed).
// ---------------------------------------------------------------------------
__global__ __launch_bounds__(256) void node_kernel(
    const __half* __restrict__ hb, const float* __restrict__ hs,
    const float* __restrict__ hd, const int* __restrict__ gcursor,
    const int* __restrict__ pairbuf, float* __restrict__ out, int N)
{
    __shared__ int2  spair[CAP];
    __shared__ float hsl[BUCKET_SRCS];
    __shared__ int   cnt[BUCKET_SRCS];
    __shared__ int   excl[BUCKET_SRCS];
    __shared__ int   lcur[BUCKET_SRCS];
    __shared__ int   perm[BUCKET_SRCS];

    const int t = threadIdx.x;
    const int b = blockIdx.x;
    const int M = min(gcursor[b], CAP);

    if (t < BUCKET_SRCS) {
        int node = b * BUCKET_SRCS + t;
        hsl[t] = (node < N) ? hs[node] : 0.f;
        cnt[t] = 0;
    }
    __syncthreads();

    const int i0 = t * 4;
    int4 p4 = *(const int4*)&pairbuf[b * CAP + i0];
    int   pkv[4] = {p4.x, p4.y, p4.z, p4.w};
    int   dofs[4], slv[4];
    float exv[4];
    int nl = 0;
    #pragma unroll
    for (int u = 0; u < 4; ++u) {
        if (i0 + u < M) {
            int pk = pkv[u];
            int sl = (pk >> 16) & 31;
            int d  = pk & 0xffff;
            float e = hsl[sl] + hd[d];
            e = (e >= 0.f) ? e : NEG_SLOPE * e;
            exv[u]  = __expf(e);
            slv[u]  = sl;
            dofs[u] = d << 7;                 // byte offset: d * OUT_DIM * 2
            atomicAdd(&cnt[sl], 1);
            nl = u + 1;
        }
    }
    __syncthreads();
    if (t < BUCKET_SRCS) {
        int raw = cnt[t];
        int v = raw;
        #pragma unroll
        for (int off = 1; off < BUCKET_SRCS; off <<= 1) {
            int u = __shfl_up(v, off, 64);
            if (t >= off) v += u;
        }
        excl[t] = v - raw;
        lcur[t] = v - raw;

        // bitonic sort (ascending) of key = deg*32 + idx across lanes 0..31
        int key = raw * 32 + t;
        #pragma unroll
        for (int k = 2; k <= 32; k <<= 1) {
            #pragma unroll
            for (int j = k >> 1; j > 0; j >>= 1) {
                int other = __shfl_xor(key, j, 64);
                bool up = (t & k) == 0;
                bool lower = (t & j) == 0;
                int mn = min(key, other), mx = max(key, other);
                key = (up == lower) ? mn : mx;
            }
        }
        perm[t] = key & 31;     // rank t -> original node-local index
    }
    __syncthreads();
    #pragma unroll
    for (int u = 0; u < 4; ++u) {
        if (u < nl) {
            int r = atomicAdd(&lcur[slv[u]], 1);
            spair[r] = make_int2(__float_as_int(exv[u]), dofs[u]);
        }
    }
    __syncthreads();

    // phase 2: slot = node (degree-balanced via perm)
    const int lane = t & 63;
    const int wave = t >> 6;
    const int slot = lane >> 3;
    const int c8   = lane & 7;
    const int loc  = perm[wave * 8 + slot];
    const int node = b * BUCKET_SRCS + loc;
    const bool valid = node < N;

    const int deg = cnt[loc];
    const int beg = excl[loc];

    int dmax = deg;
    #pragma unroll
    for (int off = 8; off < 64; off <<= 1)
        dmax = max(dmax, __shfl_xor(dmax, off, 64));

    const char* hbp = (const char*)hb + c8 * 16;   // lane-constant base

    float acc[8];
    float ssum = 0.f;
    #pragma unroll
    for (int q = 0; q < 8; ++q) acc[q] = 0.f;

    // ---- 2-stage pipelined gather loop --------------------------------
    int2  pr[4];  float ex[4];
    union { uint4 u4; __half2 h2[4]; } hv[4];

    #pragma unroll
    for (int u = 0; u < 4; ++u) {
        bool act = u < deg;
        int idx = min(beg + (act ? u : 0), CAP - 1);
        pr[u] = spair[idx];
        ex[u] = act ? __int_as_float(pr[u].x) : 0.f;
    }
    #pragma unroll
    for (int u = 0; u < 4; ++u)
        hv[u].u4 = *(const uint4*)(hbp + pr[u].y);

    for (int j = 0; j < dmax; j += 4) {
        int2  prn[4]; float exn[4];
        union { uint4 u4; __half2 h2[4]; } hvn[4];
        const int jn = j + 4;
        if (jn < dmax) {
            #pragma unroll
            for (int u = 0; u < 4; ++u) {
                bool act = jn + u < deg;
                int idx = min(beg + (act ? jn + u : 0), CAP - 1);
                prn[u] = spair[idx];
                exn[u] = act ? __int_as_float(prn[u].x) : 0.f;
            }
            #pragma unroll
            for (int u = 0; u < 4; ++u)
                hvn[u].u4 = *(const uint4*)(hbp + prn[u].y);
        } else {
            #pragma unroll
            for (int u = 0; u < 4; ++u) { exn[u] = 0.f; hvn[u].u4 = hv[u].u4; }
        }

        #pragma unroll
        for (int u = 0; u < 4; ++u) {
            ssum += ex[u];
            #pragma unroll
            for (int q = 0; q < 4; ++q) {
                acc[2 * q]     = fmaf(ex[u], __low2float(hv[u].h2[q]),  acc[2 * q]);
                acc[2 * q + 1] = fmaf(ex[u], __high2float(hv[u].h2[q]), acc[2 * q + 1]);
            }
        }

        #pragma unroll
        for (int u = 0; u < 4; ++u) { ex[u] = exn[u]; hv[u].u4 = hvn[u].u4; }
    }

    if (valid) {
        float inv = (deg > 0) ? 1.f / ssum : 0.f;
        float o[8];
        #pragma unroll
        for (int q = 0; q < 8; ++q) {
            float v = acc[q] * inv;
            o[q] = (v > 0.f) ? v : (__expf(v) - 1.f);
        }
        float4 o0 = {o[0], o[1], o[2], o[3]};
        float4 o1 = {o[4], o[5], o[6], o[7]};
        *(float4*)&out[(size_t)node * OUT_DIM + c8 * 8] = o0;
        *(float4*)&out[(size_t)node * OUT_DIM + c8 * 8 + 4] = o1;
    }
}

// ---------------------------------------------------------------------------
extern "C" void kernel_launch(void* const* d_in, const int* in_sizes, int n_in,
                              void* d_out, int out_size, void* d_ws, size_t ws_size,
                              hipStream_t stream)
{
    const float* input = (const float*)d_in[0];
    const int*   edge  = (const int*)d_in[1];
    const float* W     = (const float*)d_in[2];
    const float* a     = (const float*)d_in[3];
    float* out = (float*)d_out;

    const int N = in_sizes[0] / IN_DIM;
    const int E = in_sizes[1] / 2;
    const int* src = edge;
    const int* dst = edge + E;

    const int NBK = (N + BUCKET_SRCS - 1) / BUCKET_SRCS;   // 1563
    const int PB  = (E + PA_CHUNK - 1) / PA_CHUNK;         // 98
    const int GB  = (N + GR - 1) / GR;                     // 782

    size_t idx = 0;
    int* gcursor = (int*)d_ws + idx; idx += MAXBK;
    int* pairbuf = (int*)d_ws + idx; idx += (size_t)NBK * CAP;
    __half* hb = (__half*)((int*)d_ws + idx); idx += (size_t)N * OUT_DIM / 2;
    float* hs = (float*)((int*)d_ws + idx); idx += N;
    float* hd = (float*)((int*)d_ws + idx); idx += N;
    __half* Wt_g = (__half*)((int*)d_ws + idx); idx += OUT_DIM * IN_DIM / 2;

    init_kernel<<<32, 256, 0, stream>>>(W, gcursor, Wt_g);
    fused_gp<<<PB + GB, 256, 0, stream>>>(
        input, Wt_g, a, hb, hs, hd, src, dst, gcursor, pairbuf, E, NBK, PB, N);
    node_kernel<<<NBK, 256, 0, stream>>>(hb, hs, hd, gcursor, pairbuf, out, N);
}

// Round 7
// 112.629 us; speedup vs baseline: 2.2562x; 1.0296x over previous
//
#include <hip/hip_runtime.h>
#include <hip/hip_fp16.h>
#include <math.h>

#define IN_DIM 128
#define OUT_DIM 64
#define NEG_SLOPE 0.2f

// Bucket = 32 consecutive src ids. CAP = 1024 edges/bucket (mean 512 for
// E=800K,N=50K). N < 65536 so dst fits 16 bits in the packed word.
#define BUCKET_SRCS 32
#define CAP 1024
#define MAXBK 2048

typedef _Float16 half8 __attribute__((ext_vector_type(8)));
typedef float floatx4 __attribute__((ext_vector_type(4)));

#define GR 64
#define PA_CHUNK 4096

// ---------------------------------------------------------------------------
// Fused kernel: partition blocks FIRST, gemm blocks after. (round-0 artifact;
// R19 = full revert to the best-measured passing kernel after R18's
// zero-init-free scheme proved replay-nondeterministic.)
// ---------------------------------------------------------------------------
__global__ __launch_bounds__(256) void fused_gp(
    const float* __restrict__ in, const float* __restrict__ W,
    const float* __restrict__ a, __half* __restrict__ hb,
    float* __restrict__ hs, float* __restrict__ hd,
    const int* __restrict__ src, const int* __restrict__ dst,
    int* __restrict__ gcursor, int* __restrict__ pairbuf,
    int E, int NBK, int PB, int N)
{
    __shared__ union {
        struct { _Float16 Al[GR][IN_DIM]; _Float16 Wt[OUT_DIM][IN_DIM + 8]; } g;
        struct { int lcount[MAXBK]; int lbase[MAXBK]; int lrun[MAXBK]; } p;
    } sm;

    const int t = threadIdx.x;

    if ((int)blockIdx.x < PB) {
        // ----------------------- partition phase ---------------------------
        for (int i = t; i < NBK; i += 256) sm.p.lcount[i] = 0;
        __syncthreads();

        const int base = blockIdx.x * PA_CHUNK;
        int pk[16], b[16];
        int nloc = 0;
        #pragma unroll
        for (int j = 0; j < 16; ++j) {
            int i = base + j * 256 + t;
            if (i < E) {
                int s = src[i];
                b[j]  = s >> 5;
                pk[j] = ((s & 31) << 16) | dst[i];
                atomicAdd(&sm.p.lcount[b[j]], 1);
                nloc = j + 1;
            }
        }
        __syncthreads();
        for (int i = t; i < NBK; i += 256) {
            int c = sm.p.lcount[i];
            int gb = 0;
            if (c > 0) gb = atomicAdd(&gcursor[i], c);
            sm.p.lbase[i] = i * CAP + gb;
            sm.p.lrun[i] = 0;
        }
        __syncthreads();
        for (int j = 0; j < nloc; ++j) {
            int r = atomicAdd(&sm.p.lrun[b[j]], 1);
            int pos = sm.p.lbase[b[j]] + r;
            if (pos - b[j] * CAP < CAP)      // capacity guard (memory safety)
                pairbuf[pos] = pk[j];
        }
        return;
    }

    // ------------------------- gemm phase ----------------------------------
    const int r0 = (blockIdx.x - PB) * GR;

    #pragma unroll
    for (int i = 0; i < 8; ++i) {
        int q = i * 256 + t;
        int row = q >> 5;
        int kq  = (q & 31) * 4;
        int grow = r0 + row; if (grow >= N) grow = N - 1;
        float4 v = *(const float4*)&in[(size_t)grow * IN_DIM + kq];
        union { __half2 h2[2]; uint2 u; } cv;
        cv.h2[0] = __floats2half2_rn(v.x, v.y);
        cv.h2[1] = __floats2half2_rn(v.z, v.w);
        *(uint2*)&sm.g.Al[row][kq] = cv.u;
    }
    #pragma unroll
    for (int i = 0; i < 8; ++i) {
        int q = i * 256 + t;
        int k  = q >> 4;
        int n4 = (q & 15) * 4;
        float4 v = *(const float4*)&W[(size_t)k * OUT_DIM + n4];
        sm.g.Wt[n4 + 0][k] = (_Float16)v.x;
        sm.g.Wt[n4 + 1][k] = (_Float16)v.y;
        sm.g.Wt[n4 + 2][k] = (_Float16)v.z;
        sm.g.Wt[n4 + 3][k] = (_Float16)v.w;
    }
    __syncthreads();

    const int lane = t & 63;
    const int wave = t >> 6;
    const int m16  = lane & 15;
    const int quad = lane >> 4;

    floatx4 acc[4];
    #pragma unroll
    for (int nt = 0; nt < 4; ++nt) acc[nt] = (floatx4){0.f, 0.f, 0.f, 0.f};

    #pragma unroll
    for (int kc = 0; kc < 4; ++kc) {
        half8 af = *(const half8*)&sm.g.Al[wave * 16 + m16][kc * 32 + quad * 8];
        #pragma unroll
        for (int nt = 0; nt < 4; ++nt) {
            half8 bf = *(const half8*)&sm.g.Wt[nt * 16 + m16][kc * 32 + quad * 8];
            acc[nt] = __builtin_amdgcn_mfma_f32_16x16x32_f16(af, bf, acc[nt], 0, 0, 0);
        }
    }
    __syncthreads();   // Al dead from here; Crep aliases it

    _Float16 (*Crep)[OUT_DIM + 8] = (_Float16(*)[OUT_DIM + 8])&sm.g.Al[0][0];

    float asl[4], adl[4];
    #pragma unroll
    for (int nt = 0; nt < 4; ++nt) {
        asl[nt] = a[nt * 16 + m16];
        adl[nt] = a[OUT_DIM + nt * 16 + m16];
    }
    #pragma unroll
    for (int r = 0; r < 4; ++r) {
        float ps = 0.f, pd = 0.f;
        #pragma unroll
        for (int nt = 0; nt < 4; ++nt) {
            ps = fmaf(acc[nt][r], asl[nt], ps);
            pd = fmaf(acc[nt][r], adl[nt], pd);
        }
        #pragma unroll
        for (int off = 1; off < 16; off <<= 1) {
            ps += __shfl_xor(ps, off, 64);
            pd += __shfl_xor(pd, off, 64);
        }
        if (m16 == 0) {
            int row = r0 + wave * 16 + quad * 4 + r;
            if (row < N) { hs[row] = ps; hd[row] = pd; }
        }
    }

    #pragma unroll
    for (int nt = 0; nt < 4; ++nt)
        #pragma unroll
        for (int r = 0; r < 4; ++r)
            Crep[wave * 16 + quad * 4 + r][nt * 16 + m16] = (_Float16)acc[nt][r];
    __syncthreads();
    #pragma unroll
    for (int i = 0; i < 2; ++i) {
        int idx = i * 256 + t;
        int row = idx >> 3;
        int seg = idx & 7;
        int gr2 = r0 + row;
        if (gr2 < N) {
            uint4 v = *(const uint4*)&Crep[row][seg * 8];
            *(uint4*)&hb[(size_t)gr2 * OUT_DIM + seg * 8] = v;
        }
    }
}

// ---------------------------------------------------------------------------
// Kernel 3: one block per bucket (32 nodes).
// Phase 1: counting-sort edges into LDS (exp, dst) pairs.
// Wave 0 bitonic-sorts the 32 nodes by degree; rank r -> wave r>>3,
// slot r&7, so each wave's 8 nodes have near-equal degrees.
// Phase 2: slot = node, unrolled x4 (4 hb gathers in flight).
// ---------------------------------------------------------------------------
__global__ __launch_bounds__(256) void node_kernel(
    const __half* __restrict__ hb, const float* __restrict__ hs,
    const float* __restrict__ hd, const int* __restrict__ gcursor,
    const int* __restrict__ pairbuf, float* __restrict__ out, int N)
{
    __shared__ int2  spair[CAP];
    __shared__ float hsl[BUCKET_SRCS];
    __shared__ int   cnt[BUCKET_SRCS];
    __shared__ int   excl[BUCKET_SRCS];
    __shared__ int   lcur[BUCKET_SRCS];
    __shared__ int   perm[BUCKET_SRCS];

    const int t = threadIdx.x;
    const int b = blockIdx.x;
    const int M = min(gcursor[b], CAP);

    if (t < BUCKET_SRCS) {
        int node = b * BUCKET_SRCS + t;
        hsl[t] = (node < N) ? hs[node] : 0.f;
        cnt[t] = 0;
    }
    __syncthreads();

    int   dloc[CAP / 256], slv[CAP / 256];
    float exv[CAP / 256];
    int nl = 0;
    #pragma unroll
    for (int j = 0; j < CAP / 256; ++j) {
        int i = j * 256 + t;
        if (i < M) {
            int pk = pairbuf[b * CAP + i];
            int sl = (pk >> 16) & 31;
            int d  = pk & 0xffff;
            float e = hsl[sl] + hd[d];
            e = (e >= 0.f) ? e : NEG_SLOPE * e;
            float ex = __expf(e);
            atomicAdd(&cnt[sl], 1);
            dloc[j] = d; slv[j] = sl; exv[j] = ex;
            nl = j + 1;
        }
    }
    __syncthreads();
    if (t < BUCKET_SRCS) {
        int raw = cnt[t];
        int v = raw;
        #pragma unroll
        for (int off = 1; off < BUCKET_SRCS; off <<= 1) {
            int u = __shfl_up(v, off, 64);
            if (t >= off) v += u;
        }
        excl[t] = v - raw;
        lcur[t] = v - raw;

        // bitonic sort (ascending) of key = deg*32 + idx across lanes 0..31
        int key = raw * 32 + t;
        #pragma unroll
        for (int k = 2; k <= 32; k <<= 1) {
            #pragma unroll
            for (int j = k >> 1; j > 0; j >>= 1) {
                int other = __shfl_xor(key, j, 64);
                bool up = (t & k) == 0;
                bool lower = (t & j) == 0;
                int mn = min(key, other), mx = max(key, other);
                key = (up == lower) ? mn : mx;
            }
        }
        perm[t] = key & 31;     // rank t -> original node-local index
    }
    __syncthreads();
    for (int j = 0; j < nl; ++j) {
        int r = atomicAdd(&lcur[slv[j]], 1);
        spair[r] = make_int2(__float_as_int(exv[j]), dloc[j]);
    }
    __syncthreads();

    // phase 2: slot = node (degree-balanced via perm)
    const int lane = t & 63;
    const int wave = t >> 6;
    const int slot = lane >> 3;
    const int c8   = lane & 7;
    const int loc  = perm[wave * 8 + slot];
    const int node = b * BUCKET_SRCS + loc;
    const bool valid = node < N;

    const int deg = cnt[loc];
    const int beg = excl[loc];

    int dmax = deg;
    #pragma unroll
    for (int off = 8; off < 64; off <<= 1)
        dmax = max(dmax, __shfl_xor(dmax, off, 64));

    float acc[8];
    float ssum = 0.f;
    #pragma unroll
    for (int q = 0; q < 8; ++q) acc[q] = 0.f;

    for (int j = 0; j < dmax; j += 4) {
        int2 pr[4];
        float ex[4];
        #pragma unroll
        for (int u = 0; u < 4; ++u) {
            bool act = j + u < deg;
            pr[u] = spair[beg + (act ? j + u : 0)];
            ex[u] = act ? __int_as_float(pr[u].x) : 0.f;
            ssum += ex[u];
        }
        union { uint4 u4; __half2 h2[4]; } hv[4];
        #pragma unroll
        for (int u = 0; u < 4; ++u)
            hv[u].u4 = *(const uint4*)&hb[(size_t)pr[u].y * OUT_DIM + c8 * 8];
        #pragma unroll
        for (int u = 0; u < 4; ++u)
            #pragma unroll
            for (int q = 0; q < 4; ++q) {
                acc[2 * q]     = fmaf(ex[u], __low2float(hv[u].h2[q]),  acc[2 * q]);
                acc[2 * q + 1] = fmaf(ex[u], __high2float(hv[u].h2[q]), acc[2 * q + 1]);
            }
    }

    if (valid) {
        float inv = (deg > 0) ? 1.f / ssum : 0.f;
        float o[8];
        #pragma unroll
        for (int q = 0; q < 8; ++q) {
            float v = acc[q] * inv;
            o[q] = (v > 0.f) ? v : (__expf(v) - 1.f);
        }
        float4 o0 = {o[0], o[1], o[2], o[3]};
        float4 o1 = {o[4], o[5], o[6], o[7]};
        *(float4*)&out[(size_t)node * OUT_DIM + c8 * 8] = o0;
        *(float4*)&out[(size_t)node * OUT_DIM + c8 * 8 + 4] = o1;
    }
}

// ---------------------------------------------------------------------------
extern "C" void kernel_launch(void* const* d_in, const int* in_sizes, int n_in,
                              void* d_out, int out_size, void* d_ws, size_t ws_size,
                              hipStream_t stream)
{
    const float* input = (const float*)d_in[0];
    const int*   edge  = (const int*)d_in[1];
    const float* W     = (const float*)d_in[2];
    const float* a     = (const float*)d_in[3];
    float* out = (float*)d_out;

    const int N = in_sizes[0] / IN_DIM;
    const int E = in_sizes[1] / 2;
    const int* src = edge;
    const int* dst = edge + E;

    const int NBK = (N + BUCKET_SRCS - 1) / BUCKET_SRCS;   // 1563
    const int PB  = (E + PA_CHUNK - 1) / PA_CHUNK;         // 196
    const int GB  = (N + GR - 1) / GR;                     // 782

    size_t idx = 0;
    int* gcursor = (int*)d_ws + idx; idx += MAXBK;
    int* pairbuf = (int*)d_ws + idx; idx += (size_t)NBK * CAP;
    __half* hb = (__half*)((int*)d_ws + idx); idx += (size_t)N * OUT_DIM / 2;
    float* hs = (float*)((int*)d_ws + idx); idx += N;
    float* hd = (float*)((int*)d_ws + idx); idx += N;

    hipMemsetAsync(gcursor, 0, MAXBK * sizeof(int), stream);
    fused_gp<<<PB + GB, 256, 0, stream>>>(
        input, W, a, hb, hs, hd, src, dst, gcursor, pairbuf, E, NBK, PB, N);
    node_kernel<<<NBK, 256, 0, stream>>>(hb, hs, hd, gcursor, pairbuf, out, N);
}